// Round 10
// baseline (533.804 us; speedup 1.0000x reference)
//
#include <hip/hip_runtime.h>

#define NN   100000
#define NE   1600000
#define DIM  128
#define NBKT 391                  // ceil(NN/256) buckets of 256 nodes
#define EPB  4096                 // edges per binning block (R10: was 16384)
#define NBLK 391                  // ceil(NE/EPB) -- 4x binning parallelism
#define CASTB 12500               // cast_x blocks (NN*DIM/4/256)
#define CWB   384                 // castw blocks (3*128*256/256)
#define FNB  64                   // nodes per fused block (work-stolen by 16 waves)
#define FGB  ((NN + FNB - 1) / FNB)    // 1563 fused blocks (tail = 32 nodes)

// Ledger: dense gather (1 node/wave, 4 slots x 16 chunks, 2 chains) = 58us is
// the structural ceiling (~7TB/s L2 random-line service; R0 chains, R2 nt,
// R3-R6 sliced variants all bracket it).  R8 banked 445.5 (split pipeline).
// R9 fusion = 96us k_gl: static 4-nodes-per-wave + barrier -> straggler
// (max-of-16 Poisson sums ~1.35x) ate the fusion savings.  R10: LDS ticket
// work-stealing equalizes waves; EPB 4096 quadruples bin2/hist parallelism
// (98 blocks left >half the CUs idle -- prep tier ~180us is the other target).

typedef short          s16x8 __attribute__((ext_vector_type(8)));
typedef unsigned short u16x8 __attribute__((ext_vector_type(8)));
typedef float          f32x4 __attribute__((ext_vector_type(4)));

__device__ __forceinline__ unsigned short f2b(float f) {
    unsigned u = __float_as_uint(f);
    unsigned r = ((u >> 16) & 1u) + 0x7FFFu;   // RNE
    return (unsigned short)((u + r) >> 16);
}
__device__ __forceinline__ float b2f(unsigned short h) {
    return __uint_as_float(((unsigned)h) << 16);
}

// ---- fused prep: [0,NBLK) hist | [NBLK,NBLK+CASTB) cast_x | rest castw ----
__global__ void k_prep(const float* __restrict__ x, unsigned short* __restrict__ xb,
                       const int* __restrict__ dst, int* __restrict__ hist,
                       const float* __restrict__ W1l, const float* __restrict__ W1r,
                       const float* __restrict__ W2l, const float* __restrict__ W2r,
                       const float* __restrict__ W3l, const float* __restrict__ W3r,
                       unsigned short* __restrict__ Wt1, unsigned short* __restrict__ Wt2,
                       unsigned short* __restrict__ Wt3) {
    __shared__ int lh[NBKT];
    int t = threadIdx.x, b = blockIdx.x;
    if (b < NBLK) {
        // bucket histogram -> hist[k*NBLK + b] (bucket-major)
        for (int j = t; j < NBKT; j += 256) lh[j] = 0;
        __syncthreads();
        int base = b * EPB;
        int end = base + EPB; if (end > NE) end = NE;
        for (int i = base + t; i < end; i += 256) atomicAdd(&lh[dst[i] >> 8], 1);
        __syncthreads();
        for (int j = t; j < NBKT; j += 256) hist[j * NBLK + b] = lh[j];
    } else if (b < NBLK + CASTB) {
        // fp32 -> bf16 feature cast, dense layout (fully sequential both sides)
        int i = (b - NBLK) * 256 + t;
        float4 v = ((const float4*)x)[i];
        ushort4 o;
        o.x = f2b(v.x); o.y = f2b(v.y); o.z = f2b(v.z); o.w = f2b(v.w);
        ((ushort4*)xb)[i] = o;
    } else {
        // weight cast: Wt[n][k] = bf16( k<128 ? Wl[k][n] : Wr[k-128][n] )
        int i = (b - NBLK - CASTB) * 256 + t;   // 3 * 128 * 256
        int L = i >> 15;
        int rem = i & 32767;
        int n = rem >> 8;
        int k = rem & 255;
        const float* Wl = (L == 0) ? W1l : (L == 1) ? W2l : W3l;
        const float* Wr = (L == 0) ? W1r : (L == 1) ? W2r : W3r;
        unsigned short* Wt = (L == 0) ? Wt1 : (L == 1) ? Wt2 : Wt3;
        float v = (k < 128) ? Wl[k * 128 + n] : Wr[(k - 128) * 128 + n];
        Wt[n * 256 + k] = f2b(v);
    }
}

// ---- phase 2a: per-bucket row scan (exclusive over the 391 block counts) ----
__global__ void k_scanrow(int* __restrict__ hist, int* __restrict__ row_total) {
    __shared__ int sh[512];
    int k = blockIdx.x, t = threadIdx.x;
    int v = (t < NBLK) ? hist[k * NBLK + t] : 0;
    sh[t] = v;
    __syncthreads();
    for (int off = 1; off < 512; off <<= 1) {
        int a = (t >= off) ? sh[t - off] : 0;
        __syncthreads();
        sh[t] += a;
        __syncthreads();
    }
    if (t < NBLK) hist[k * NBLK + t] = sh[t] - v;   // exclusive within row
    if (t == 511) row_total[k] = sh[511];
}

// ---- phase 3: bin edges; bucket-base scan folded in (pair-blocked LDS scan)
// Each block recomputes the 391-total exclusive scan (~1us, concurrent);
// block 0 persists bbase for k_build.  word = (src<<8)|(dst&255).
__global__ void k_bin2(const int* __restrict__ src, const int* __restrict__ dst,
                       const int* __restrict__ hist, const int* __restrict__ row_total,
                       int* __restrict__ bbase, int* __restrict__ binned) {
    __shared__ int s_base[NBKT];
    __shared__ int s_cnt[NBKT];
    __shared__ int ps[256];
    int t = threadIdx.x, b = blockIdx.x;
    // pair-blocked exclusive scan of row_total[0..NBKT)
    int a0 = (2 * t     < NBKT) ? row_total[2 * t]     : 0;
    int a1 = (2 * t + 1 < NBKT) ? row_total[2 * t + 1] : 0;
    ps[t] = a0 + a1;
    __syncthreads();
    for (int off = 1; off < 256; off <<= 1) {
        int v = (t >= off) ? ps[t - off] : 0;
        __syncthreads();
        ps[t] += v;
        __syncthreads();
    }
    int pe = ps[t] - (a0 + a1);            // exclusive pair-prefix
    if (2 * t     < NBKT) s_base[2 * t]     = pe;
    if (2 * t + 1 < NBKT) s_base[2 * t + 1] = pe + a0;
    __syncthreads();
    if (b == 0) {                          // persist for k_build
        for (int j = t; j < NBKT; j += 256) bbase[j] = s_base[j];
        if (t == 0) bbase[NBKT] = NE;
    }
    for (int j = t; j < NBKT; j += 256) {
        s_base[j] += hist[j * NBLK + b];
        s_cnt[j] = 0;
    }
    __syncthreads();
    int base = b * EPB;
    int end = base + EPB; if (end > NE) end = NE;
    for (int i = base + t; i < end; i += 256) {
        int d = dst[i];
        int k = d >> 8;
        int w = (src[i] << 8) | (d & 255);
        int lpos = atomicAdd(&s_cnt[k], 1);
        binned[s_base[k] + lpos] = w;
    }
}

// ---- per-bucket CSR build: LDS degree hist + scan + staged coalesced write.
// Gather metadata packed per node: meta = {row_start, deg, deg_inv_bits, 0}.
__global__ void k_build(const int* __restrict__ binned,
                        const int* __restrict__ bucket_base,
                        int* __restrict__ csr, int4* __restrict__ meta) {
    __shared__ int s_deg[256], s_scan[256], s_cur[256];
    __shared__ int stage[8192];
    int b = blockIdx.x, t = threadIdx.x;
    int base = bucket_base[b], end = bucket_base[b + 1];
    int cnt = end - base;
    s_deg[t] = 0;
    __syncthreads();
    for (int i = t; i < cnt; i += 256)
        atomicAdd(&s_deg[binned[base + i] & 255], 1);
    __syncthreads();
    s_scan[t] = s_deg[t];
    __syncthreads();
    for (int off = 1; off < 256; off <<= 1) {
        int a = (t >= off) ? s_scan[t - off] : 0;
        __syncthreads();
        s_scan[t] += a;
        __syncthreads();
    }
    int excl = s_scan[t] - s_deg[t];
    s_cur[t] = excl;
    int node = b * 256 + t;
    if (node < NN) {
        int d = s_deg[t];
        float di = (d > 0) ? 1.0f / (float)d : 0.0f;
        int4 M; M.x = base + excl; M.y = d; M.z = __float_as_int(di); M.w = 0;
        meta[node] = M;
    }
    __syncthreads();
    for (int i = t; i < cnt; i += 256) {
        int w = binned[base + i];           // L2-hot second read
        int pos = atomicAdd(&s_cur[w & 255], 1);
        int s = w >> 8;
        if (pos < 8192) stage[pos] = s;
        else            csr[base + pos] = s;   // overflow fallback (not expected)
    }
    __syncthreads();
    int m = cnt < 8192 ? cnt : 8192;
    for (int i = t; i < m; i += 256) csr[base + i] = stage[i];
}

// ---- fused gather+linear, work-stealing: 64 nodes/block, 16 waves.
// Phase G: waves grab nodes off an LDS ticket queue (R9 straggler fix: static
//   4/wave + barrier cost max-of-16 Poisson ~1.35x).  Per node: all 64 lanes,
//   4 neighbor slots x 16 col-chunks, 2 chains -- R8-identical inner loop;
//   mean -> LDS sM (chunk^node swizzle).
// Phase L: 16 waves x 2 (tile,mt) tasks; A=weights (LDS, fragment order),
//   B = mean (LDS) || own-node feat (global); store bias+[relu] result.
// MODE 0: relu, bf16 out; MODE 1: no act, fp32 out.
template <int MODE>
__global__ void __launch_bounds__(1024, 8)
k_gl(const unsigned short* __restrict__ feat,
     const int4* __restrict__ meta, const int* __restrict__ csr,
     const unsigned short* __restrict__ Wt,
     const float* __restrict__ bias, void* __restrict__ out) {
    __shared__ s16x8 sW[4096];             // 64 KB weights, fragment order
    __shared__ s16x8 sM[FNB * 16];         // 16 KB mean, chunk^(node&15) swizzle
    __shared__ int s_next;
    int t = threadIdx.x;
    if (t == 0) s_next = 0;
    const s16x8* wp = (const s16x8*)Wt;
    // stage weights: A-frag for tile (mt,kt): m = mt*16+(ln&15), kc = kt*4+(ln>>4)
#pragma unroll
    for (int it = 0; it < 4; it++) {
        int ci = it * 1024 + t;
        int frag = ci >> 6, ln = ci & 63;
        int mt = frag >> 3, kt = frag & 7;
        int m = mt * 16 + (ln & 15);
        int kc = kt * 4 + (ln >> 4);
        sW[ci] = wp[m * 32 + kc];
    }
    __syncthreads();                       // s_next visible (sW also staged)

    int lane = t & 63;
    int n0   = blockIdx.x * FNB;
    int q = lane >> 4, c = lane & 15;      // q: neighbor slot, c: 16B col chunk
    const u16x8* fp = (const u16x8*)feat;

    // ---- Phase G: ticket loop ----
    for (;;) {
        int nb0 = 0;
        if (lane == 0) nb0 = atomicAdd(&s_next, 1);
        int nb = __shfl(nb0, 0, 64);       // wave-uniform ticket
        if (nb >= FNB) break;
        int n = n0 + nb;
        if (n >= NN) continue;             // tail block: drain queue (uniform)
        int4 M = meta[n];
        int base = M.x;
        int d    = M.y;
        float s  = __int_as_float(M.z);
        float acc0[8], acc1[8];
#pragma unroll
        for (int e = 0; e < 8; e++) { acc0[e] = 0.0f; acc1[e] = 0.0f; }
        int j = q;
        for (; j + 4 < d; j += 8) {
            int s0 = csr[base + j];
            int s1 = csr[base + j + 4];
            u16x8 v0 = fp[s0 * 16 + c];
            u16x8 v1 = fp[s1 * 16 + c];
#pragma unroll
            for (int e = 0; e < 8; e++) { acc0[e] += b2f(v0[e]); acc1[e] += b2f(v1[e]); }
        }
        if (j < d) {
            int s0 = csr[base + j];
            u16x8 v0 = fp[s0 * 16 + c];
#pragma unroll
            for (int e = 0; e < 8; e++) acc0[e] += b2f(v0[e]);
        }
#pragma unroll
        for (int e = 0; e < 8; e++) acc0[e] += acc1[e];
#pragma unroll
        for (int e = 0; e < 8; e++) {
            acc0[e] += __shfl_xor(acc0[e], 16, 64);
            acc0[e] += __shfl_xor(acc0[e], 32, 64);
        }
        if (q == 0) {
            u16x8 o;
#pragma unroll
            for (int e = 0; e < 8; e++) o[e] = f2b(acc0[e] * s);
            ((u16x8*)sM)[nb * 16 + (c ^ (nb & 15))] = o;   // swizzled
        }
    }
    __syncthreads();

    // ---- Phase L: tasks (tile,mt); task = wv*2+s, tile = task>>3, mt = task&7
    int wv = t >> 6;
    const s16x8* hp = (const s16x8*)feat;
    const f32x4* bp = (const f32x4*)bias;
#pragma unroll
    for (int s = 0; s < 2; s++) {
        int task = wv * 2 + s;
        int tile = task >> 3, mt = task & 7;
        int tn0 = n0 + tile * 16;
        if (tn0 + 15 >= NN) continue;      // tail block: tiles beyond 32 nodes
        int c2 = lane & 15, q2 = lane >> 4;
        int node = tn0 + c2;
        f32x4 acc = {0.f, 0.f, 0.f, 0.f};
        // first half: mean part (k-chunks 0..15) from LDS
        {
            s16x8 B0 = sM[(tile * 16 + c2) * 16 + ((0 * 4 + q2) ^ c2)];
            s16x8 B1 = sM[(tile * 16 + c2) * 16 + ((1 * 4 + q2) ^ c2)];
            s16x8 B2 = sM[(tile * 16 + c2) * 16 + ((2 * 4 + q2) ^ c2)];
            s16x8 B3 = sM[(tile * 16 + c2) * 16 + ((3 * 4 + q2) ^ c2)];
            acc = __builtin_amdgcn_mfma_f32_16x16x32_bf16(sW[(mt * 8 + 0) * 64 + lane], B0, acc, 0, 0, 0);
            acc = __builtin_amdgcn_mfma_f32_16x16x32_bf16(sW[(mt * 8 + 1) * 64 + lane], B1, acc, 0, 0, 0);
            acc = __builtin_amdgcn_mfma_f32_16x16x32_bf16(sW[(mt * 8 + 2) * 64 + lane], B2, acc, 0, 0, 0);
            acc = __builtin_amdgcn_mfma_f32_16x16x32_bf16(sW[(mt * 8 + 3) * 64 + lane], B3, acc, 0, 0, 0);
        }
        // second half: own-node feature part (k-chunks 16..31) from global
        {
            s16x8 B4 = hp[node * 16 + 0 * 4 + q2];
            s16x8 B5 = hp[node * 16 + 1 * 4 + q2];
            s16x8 B6 = hp[node * 16 + 2 * 4 + q2];
            s16x8 B7 = hp[node * 16 + 3 * 4 + q2];
            acc = __builtin_amdgcn_mfma_f32_16x16x32_bf16(sW[(mt * 8 + 4) * 64 + lane], B4, acc, 0, 0, 0);
            acc = __builtin_amdgcn_mfma_f32_16x16x32_bf16(sW[(mt * 8 + 5) * 64 + lane], B5, acc, 0, 0, 0);
            acc = __builtin_amdgcn_mfma_f32_16x16x32_bf16(sW[(mt * 8 + 6) * 64 + lane], B6, acc, 0, 0, 0);
            acc = __builtin_amdgcn_mfma_f32_16x16x32_bf16(sW[(mt * 8 + 7) * 64 + lane], B7, acc, 0, 0, 0);
        }
        f32x4 bv = bp[mt * 4 + q2];        // outdims mt*16+q2*4 .. +3
        if (MODE == 0) {
            ushort4 o;
            float v0 = acc[0] + bv[0]; if (v0 < 0.f) v0 = 0.f;
            float v1 = acc[1] + bv[1]; if (v1 < 0.f) v1 = 0.f;
            float v2 = acc[2] + bv[2]; if (v2 < 0.f) v2 = 0.f;
            float v3 = acc[3] + bv[3]; if (v3 < 0.f) v3 = 0.f;
            o.x = f2b(v0); o.y = f2b(v1); o.z = f2b(v2); o.w = f2b(v3);
            ((ushort4*)out)[node * 32 + mt * 4 + q2] = o;
        } else {
            f32x4 v;
#pragma unroll
            for (int r = 0; r < 4; r++) v[r] = acc[r] + bv[r];
            ((f32x4*)out)[node * 32 + mt * 4 + q2] = v;
        }
    }
}

extern "C" void kernel_launch(void* const* d_in, const int* in_sizes, int n_in,
                              void* d_out, int out_size, void* d_ws, size_t ws_size,
                              hipStream_t stream) {
    const float* x   = (const float*)d_in[1];
    const int*   ei  = (const int*)d_in[2];
    const int*   src = ei;
    const int*   dst = ei + NE;
    const float* W1l = (const float*)d_in[3];
    const float* W1r = (const float*)d_in[4];
    const float* b1  = (const float*)d_in[5];
    const float* W2l = (const float*)d_in[6];
    const float* W2r = (const float*)d_in[7];
    const float* b2  = (const float*)d_in[8];
    const float* W3l = (const float*)d_in[9];
    const float* W3r = (const float*)d_in[10];
    const float* b3  = (const float*)d_in[11];

    // workspace carve (all 256B aligned)
    char* w = (char*)d_ws;
    auto carve = [&](size_t bytes) {
        void* p = (void*)w;
        w += (bytes + 255) & ~(size_t)255;
        return p;
    };
    int4*  meta      = (int4*)carve((size_t)NN * 16);
    int*   hist      = (int*)carve((size_t)NBKT * NBLK * 4);
    int*   row_total = (int*)carve(NBKT * 4);
    int*   bbase     = (int*)carve((NBKT + 1) * 4);
    int*   csr       = (int*)carve((size_t)NE * 4);
    unsigned short* Wt1 = (unsigned short*)carve(128 * 256 * 2);
    unsigned short* Wt2 = (unsigned short*)carve(128 * 256 * 2);
    unsigned short* Wt3 = (unsigned short*)carve(128 * 256 * 2);
    unsigned short* xb    = (unsigned short*)carve((size_t)NN * DIM * 2);
    unsigned short* h1b   = (unsigned short*)carve((size_t)NN * DIM * 2);
    unsigned short* h2b   = xb;          // x dead after layer-2 own-feat reads
    int*   binned    = (int*)h1b;        // binned (6.4 MB) dead before k_gl<0> #1

    k_prep<<<NBLK + CASTB + CWB, 256, 0, stream>>>(x, xb, dst, hist,
                                                   W1l, W1r, W2l, W2r, W3l, W3r,
                                                   Wt1, Wt2, Wt3);
    k_scanrow<<<NBKT, 512, 0, stream>>>(hist, row_total);
    k_bin2<<<NBLK, 256, 0, stream>>>(src, dst, hist, row_total, bbase, binned);
    k_build<<<NBKT, 256, 0, stream>>>(binned, bbase, csr, meta);

    // layer 1: h1 = relu(Wl*mean(xb) + Wr*xb + b)
    k_gl<0><<<FGB, 1024, 0, stream>>>(xb, meta, csr, Wt1, b1, (void*)h1b);
    // layer 2: h2 = relu(Wl*mean(h1) + Wr*h1 + b)   (h2b aliases xb)
    k_gl<0><<<FGB, 1024, 0, stream>>>(h1b, meta, csr, Wt2, b2, (void*)h2b);
    // layer 3: dx_dt = Wl*mean(h2) + Wr*h2 + b      (fp32 out)
    k_gl<1><<<FGB, 1024, 0, stream>>>(h2b, meta, csr, Wt3, b3, d_out);
}

// Round 11
// 516.438 us; speedup vs baseline: 1.0336x; 1.0336x over previous
//
#include <hip/hip_runtime.h>

#define NN   100000
#define NE   1600000
#define DIM  128
#define NBKT 391                  // ceil(NN/256) buckets of 256 nodes
#define EPB  4096                 // edges per binning block
#define NBLK 391                  // ceil(NE/EPB)
#define CASTB 12500               // cast_x blocks (NN*DIM/4/256)
#define CWB   384                 // castw blocks (3*128*256/256)
#define FNB  64                   // nodes per fused block (work-stolen by 16 waves)
#define FGB  ((NN + FNB - 1) / FNB)    // 1563 fused blocks (tail = 32 nodes)

// Ledger: dense gather inner loop (1 node/wave, 4 slots x 16 chunks, 2 chains)
// = 58us structural ceiling (~7TB/s L2 random-line service).  R8 split = 445.5.
// R9 fused static = 96us k_gl (barrier straggler ~1.35x).  R10 LDS ticket:
// s_next pushed LDS 80KB->80.5KB -> 1 block/CU (occ 70->39%), k_gl 128us --
// work-stealing never actually tested.  R11: tickets in GLOBAL (per layer x
// block, zeroed in k_build), LDS back to exactly 80KB = 2 blocks/CU.
// EPB=4096 kept (R10: prep tier -27us).

typedef short          s16x8 __attribute__((ext_vector_type(8)));
typedef unsigned short u16x8 __attribute__((ext_vector_type(8)));
typedef float          f32x4 __attribute__((ext_vector_type(4)));

__device__ __forceinline__ unsigned short f2b(float f) {
    unsigned u = __float_as_uint(f);
    unsigned r = ((u >> 16) & 1u) + 0x7FFFu;   // RNE
    return (unsigned short)((u + r) >> 16);
}
__device__ __forceinline__ float b2f(unsigned short h) {
    return __uint_as_float(((unsigned)h) << 16);
}

// ---- fused prep: [0,NBLK) hist | [NBLK,NBLK+CASTB) cast_x | rest castw ----
__global__ void k_prep(const float* __restrict__ x, unsigned short* __restrict__ xb,
                       const int* __restrict__ dst, int* __restrict__ hist,
                       const float* __restrict__ W1l, const float* __restrict__ W1r,
                       const float* __restrict__ W2l, const float* __restrict__ W2r,
                       const float* __restrict__ W3l, const float* __restrict__ W3r,
                       unsigned short* __restrict__ Wt1, unsigned short* __restrict__ Wt2,
                       unsigned short* __restrict__ Wt3) {
    __shared__ int lh[NBKT];
    int t = threadIdx.x, b = blockIdx.x;
    if (b < NBLK) {
        // bucket histogram -> hist[k*NBLK + b] (bucket-major)
        for (int j = t; j < NBKT; j += 256) lh[j] = 0;
        __syncthreads();
        int base = b * EPB;
        int end = base + EPB; if (end > NE) end = NE;
        for (int i = base + t; i < end; i += 256) atomicAdd(&lh[dst[i] >> 8], 1);
        __syncthreads();
        for (int j = t; j < NBKT; j += 256) hist[j * NBLK + b] = lh[j];
    } else if (b < NBLK + CASTB) {
        // fp32 -> bf16 feature cast, dense layout (fully sequential both sides)
        int i = (b - NBLK) * 256 + t;
        float4 v = ((const float4*)x)[i];
        ushort4 o;
        o.x = f2b(v.x); o.y = f2b(v.y); o.z = f2b(v.z); o.w = f2b(v.w);
        ((ushort4*)xb)[i] = o;
    } else {
        // weight cast: Wt[n][k] = bf16( k<128 ? Wl[k][n] : Wr[k-128][n] )
        int i = (b - NBLK - CASTB) * 256 + t;   // 3 * 128 * 256
        int L = i >> 15;
        int rem = i & 32767;
        int n = rem >> 8;
        int k = rem & 255;
        const float* Wl = (L == 0) ? W1l : (L == 1) ? W2l : W3l;
        const float* Wr = (L == 0) ? W1r : (L == 1) ? W2r : W3r;
        unsigned short* Wt = (L == 0) ? Wt1 : (L == 1) ? Wt2 : Wt3;
        float v = (k < 128) ? Wl[k * 128 + n] : Wr[(k - 128) * 128 + n];
        Wt[n * 256 + k] = f2b(v);
    }
}

// ---- phase 2a: per-bucket row scan (exclusive over the 391 block counts) ----
__global__ void k_scanrow(int* __restrict__ hist, int* __restrict__ row_total) {
    __shared__ int sh[512];
    int k = blockIdx.x, t = threadIdx.x;
    int v = (t < NBLK) ? hist[k * NBLK + t] : 0;
    sh[t] = v;
    __syncthreads();
    for (int off = 1; off < 512; off <<= 1) {
        int a = (t >= off) ? sh[t - off] : 0;
        __syncthreads();
        sh[t] += a;
        __syncthreads();
    }
    if (t < NBLK) hist[k * NBLK + t] = sh[t] - v;   // exclusive within row
    if (t == 511) row_total[k] = sh[511];
}

// ---- phase 3: bin edges; bucket-base scan folded in (pair-blocked LDS scan)
__global__ void k_bin2(const int* __restrict__ src, const int* __restrict__ dst,
                       const int* __restrict__ hist, const int* __restrict__ row_total,
                       int* __restrict__ bbase, int* __restrict__ binned) {
    __shared__ int s_base[NBKT];
    __shared__ int s_cnt[NBKT];
    __shared__ int ps[256];
    int t = threadIdx.x, b = blockIdx.x;
    // pair-blocked exclusive scan of row_total[0..NBKT)
    int a0 = (2 * t     < NBKT) ? row_total[2 * t]     : 0;
    int a1 = (2 * t + 1 < NBKT) ? row_total[2 * t + 1] : 0;
    ps[t] = a0 + a1;
    __syncthreads();
    for (int off = 1; off < 256; off <<= 1) {
        int v = (t >= off) ? ps[t - off] : 0;
        __syncthreads();
        ps[t] += v;
        __syncthreads();
    }
    int pe = ps[t] - (a0 + a1);            // exclusive pair-prefix
    if (2 * t     < NBKT) s_base[2 * t]     = pe;
    if (2 * t + 1 < NBKT) s_base[2 * t + 1] = pe + a0;
    __syncthreads();
    if (b == 0) {                          // persist for k_build
        for (int j = t; j < NBKT; j += 256) bbase[j] = s_base[j];
        if (t == 0) bbase[NBKT] = NE;
    }
    for (int j = t; j < NBKT; j += 256) {
        s_base[j] += hist[j * NBLK + b];
        s_cnt[j] = 0;
    }
    __syncthreads();
    int base = b * EPB;
    int end = base + EPB; if (end > NE) end = NE;
    for (int i = base + t; i < end; i += 256) {
        int d = dst[i];
        int k = d >> 8;
        int w = (src[i] << 8) | (d & 255);
        int lpos = atomicAdd(&s_cnt[k], 1);
        binned[s_base[k] + lpos] = w;
    }
}

// ---- per-bucket CSR build + ticket-array zeroing.
// Gather metadata packed per node: meta = {row_start, deg, deg_inv_bits, 0}.
__global__ void k_build(const int* __restrict__ binned,
                        const int* __restrict__ bucket_base,
                        int* __restrict__ csr, int4* __restrict__ meta,
                        int* __restrict__ tickets) {
    __shared__ int s_deg[256], s_scan[256], s_cur[256];
    __shared__ int stage[8192];
    int b = blockIdx.x, t = threadIdx.x;
    // zero the 3*FGB ticket counters (grid-stride; one pass covers all)
    for (int i = b * 256 + t; i < 3 * FGB; i += NBKT * 256) tickets[i] = 0;
    int base = bucket_base[b], end = bucket_base[b + 1];
    int cnt = end - base;
    s_deg[t] = 0;
    __syncthreads();
    for (int i = t; i < cnt; i += 256)
        atomicAdd(&s_deg[binned[base + i] & 255], 1);
    __syncthreads();
    s_scan[t] = s_deg[t];
    __syncthreads();
    for (int off = 1; off < 256; off <<= 1) {
        int a = (t >= off) ? s_scan[t - off] : 0;
        __syncthreads();
        s_scan[t] += a;
        __syncthreads();
    }
    int excl = s_scan[t] - s_deg[t];
    s_cur[t] = excl;
    int node = b * 256 + t;
    if (node < NN) {
        int d = s_deg[t];
        float di = (d > 0) ? 1.0f / (float)d : 0.0f;
        int4 M; M.x = base + excl; M.y = d; M.z = __float_as_int(di); M.w = 0;
        meta[node] = M;
    }
    __syncthreads();
    for (int i = t; i < cnt; i += 256) {
        int w = binned[base + i];           // L2-hot second read
        int pos = atomicAdd(&s_cur[w & 255], 1);
        int s = w >> 8;
        if (pos < 8192) stage[pos] = s;
        else            csr[base + pos] = s;   // overflow fallback (not expected)
    }
    __syncthreads();
    int m = cnt < 8192 ? cnt : 8192;
    for (int i = t; i < m; i += 256) csr[base + i] = stage[i];
}

// ---- fused gather+linear, global work-stealing: 64 nodes/block, 16 waves.
// Phase G: waves grab nodes off tickets[blockIdx.x] (GLOBAL -- R10 lesson:
//   an LDS counter pushed 80KB->80.5KB -> 1 block/CU).  Per node: all 64
//   lanes, 4 slots x 16 chunks, 2 chains (R8-identical); mean -> LDS sM.
// Phase L: 16 waves x 2 (tile,mt) tasks; A=weights (LDS, fragment order),
//   B = mean (LDS) || own-node feat (global); store bias+[relu] result.
// LDS = 64KB sW + 16KB sM = exactly 80KB -> 2 blocks/CU.
template <int MODE>
__global__ void __launch_bounds__(1024, 8)
k_gl(const unsigned short* __restrict__ feat,
     const int4* __restrict__ meta, const int* __restrict__ csr,
     const unsigned short* __restrict__ Wt,
     const float* __restrict__ bias, void* __restrict__ out,
     int* __restrict__ tickets) {
    __shared__ s16x8 sW[4096];             // 64 KB weights, fragment order
    __shared__ s16x8 sM[FNB * 16];         // 16 KB mean, chunk^(node&15) swizzle
    int t = threadIdx.x;
    const s16x8* wp = (const s16x8*)Wt;
    // stage weights: A-frag for tile (mt,kt): m = mt*16+(ln&15), kc = kt*4+(ln>>4)
#pragma unroll
    for (int it = 0; it < 4; it++) {
        int ci = it * 1024 + t;
        int frag = ci >> 6, ln = ci & 63;
        int mt = frag >> 3, kt = frag & 7;
        int m = mt * 16 + (ln & 15);
        int kc = kt * 4 + (ln >> 4);
        sW[ci] = wp[m * 32 + kc];
    }

    int lane = t & 63;
    int n0   = blockIdx.x * FNB;
    int q = lane >> 4, c = lane & 15;      // q: neighbor slot, c: 16B col chunk
    const u16x8* fp = (const u16x8*)feat;
    int* tk = tickets + blockIdx.x;        // this block's private counter

    // ---- Phase G: global ticket loop ----
    for (;;) {
        int nb0 = 0;
        if (lane == 0) nb0 = atomicAdd(tk, 1);
        int nb = __shfl(nb0, 0, 64);       // wave-uniform ticket
        if (nb >= FNB) break;
        int n = n0 + nb;
        if (n >= NN) continue;             // tail block: drain queue (uniform)
        int4 M = meta[n];
        int base = M.x;
        int d    = M.y;
        float s  = __int_as_float(M.z);
        float acc0[8], acc1[8];
#pragma unroll
        for (int e = 0; e < 8; e++) { acc0[e] = 0.0f; acc1[e] = 0.0f; }
        int j = q;
        for (; j + 4 < d; j += 8) {
            int s0 = csr[base + j];
            int s1 = csr[base + j + 4];
            u16x8 v0 = fp[s0 * 16 + c];
            u16x8 v1 = fp[s1 * 16 + c];
#pragma unroll
            for (int e = 0; e < 8; e++) { acc0[e] += b2f(v0[e]); acc1[e] += b2f(v1[e]); }
        }
        if (j < d) {
            int s0 = csr[base + j];
            u16x8 v0 = fp[s0 * 16 + c];
#pragma unroll
            for (int e = 0; e < 8; e++) acc0[e] += b2f(v0[e]);
        }
#pragma unroll
        for (int e = 0; e < 8; e++) acc0[e] += acc1[e];
#pragma unroll
        for (int e = 0; e < 8; e++) {
            acc0[e] += __shfl_xor(acc0[e], 16, 64);
            acc0[e] += __shfl_xor(acc0[e], 32, 64);
        }
        if (q == 0) {
            u16x8 o;
#pragma unroll
            for (int e = 0; e < 8; e++) o[e] = f2b(acc0[e] * s);
            ((u16x8*)sM)[nb * 16 + (c ^ (nb & 15))] = o;   // swizzled
        }
    }
    __syncthreads();

    // ---- Phase L: tasks (tile,mt); task = wv*2+s, tile = task>>3, mt = task&7
    int wv = t >> 6;
    const s16x8* hp = (const s16x8*)feat;
    const f32x4* bp = (const f32x4*)bias;
#pragma unroll
    for (int s = 0; s < 2; s++) {
        int task = wv * 2 + s;
        int tile = task >> 3, mt = task & 7;
        int tn0 = n0 + tile * 16;
        if (tn0 + 15 >= NN) continue;      // tail block: tiles beyond 32 nodes
        int c2 = lane & 15, q2 = lane >> 4;
        int node = tn0 + c2;
        f32x4 acc = {0.f, 0.f, 0.f, 0.f};
        // first half: mean part (k-chunks 0..15) from LDS
        {
            s16x8 B0 = sM[(tile * 16 + c2) * 16 + ((0 * 4 + q2) ^ c2)];
            s16x8 B1 = sM[(tile * 16 + c2) * 16 + ((1 * 4 + q2) ^ c2)];
            s16x8 B2 = sM[(tile * 16 + c2) * 16 + ((2 * 4 + q2) ^ c2)];
            s16x8 B3 = sM[(tile * 16 + c2) * 16 + ((3 * 4 + q2) ^ c2)];
            acc = __builtin_amdgcn_mfma_f32_16x16x32_bf16(sW[(mt * 8 + 0) * 64 + lane], B0, acc, 0, 0, 0);
            acc = __builtin_amdgcn_mfma_f32_16x16x32_bf16(sW[(mt * 8 + 1) * 64 + lane], B1, acc, 0, 0, 0);
            acc = __builtin_amdgcn_mfma_f32_16x16x32_bf16(sW[(mt * 8 + 2) * 64 + lane], B2, acc, 0, 0, 0);
            acc = __builtin_amdgcn_mfma_f32_16x16x32_bf16(sW[(mt * 8 + 3) * 64 + lane], B3, acc, 0, 0, 0);
        }
        // second half: own-node feature part (k-chunks 16..31) from global
        {
            s16x8 B4 = hp[node * 16 + 0 * 4 + q2];
            s16x8 B5 = hp[node * 16 + 1 * 4 + q2];
            s16x8 B6 = hp[node * 16 + 2 * 4 + q2];
            s16x8 B7 = hp[node * 16 + 3 * 4 + q2];
            acc = __builtin_amdgcn_mfma_f32_16x16x32_bf16(sW[(mt * 8 + 4) * 64 + lane], B4, acc, 0, 0, 0);
            acc = __builtin_amdgcn_mfma_f32_16x16x32_bf16(sW[(mt * 8 + 5) * 64 + lane], B5, acc, 0, 0, 0);
            acc = __builtin_amdgcn_mfma_f32_16x16x32_bf16(sW[(mt * 8 + 6) * 64 + lane], B6, acc, 0, 0, 0);
            acc = __builtin_amdgcn_mfma_f32_16x16x32_bf16(sW[(mt * 8 + 7) * 64 + lane], B7, acc, 0, 0, 0);
        }
        f32x4 bv = bp[mt * 4 + q2];        // outdims mt*16+q2*4 .. +3
        if (MODE == 0) {
            ushort4 o;
            float v0 = acc[0] + bv[0]; if (v0 < 0.f) v0 = 0.f;
            float v1 = acc[1] + bv[1]; if (v1 < 0.f) v1 = 0.f;
            float v2 = acc[2] + bv[2]; if (v2 < 0.f) v2 = 0.f;
            float v3 = acc[3] + bv[3]; if (v3 < 0.f) v3 = 0.f;
            o.x = f2b(v0); o.y = f2b(v1); o.z = f2b(v2); o.w = f2b(v3);
            ((ushort4*)out)[node * 32 + mt * 4 + q2] = o;
        } else {
            f32x4 v;
#pragma unroll
            for (int r = 0; r < 4; r++) v[r] = acc[r] + bv[r];
            ((f32x4*)out)[node * 32 + mt * 4 + q2] = v;
        }
    }
}

extern "C" void kernel_launch(void* const* d_in, const int* in_sizes, int n_in,
                              void* d_out, int out_size, void* d_ws, size_t ws_size,
                              hipStream_t stream) {
    const float* x   = (const float*)d_in[1];
    const int*   ei  = (const int*)d_in[2];
    const int*   src = ei;
    const int*   dst = ei + NE;
    const float* W1l = (const float*)d_in[3];
    const float* W1r = (const float*)d_in[4];
    const float* b1  = (const float*)d_in[5];
    const float* W2l = (const float*)d_in[6];
    const float* W2r = (const float*)d_in[7];
    const float* b2  = (const float*)d_in[8];
    const float* W3l = (const float*)d_in[9];
    const float* W3r = (const float*)d_in[10];
    const float* b3  = (const float*)d_in[11];

    // workspace carve (all 256B aligned)
    char* w = (char*)d_ws;
    auto carve = [&](size_t bytes) {
        void* p = (void*)w;
        w += (bytes + 255) & ~(size_t)255;
        return p;
    };
    int4*  meta      = (int4*)carve((size_t)NN * 16);
    int*   tickets   = (int*)carve((size_t)3 * FGB * 4);
    int*   hist      = (int*)carve((size_t)NBKT * NBLK * 4);
    int*   row_total = (int*)carve(NBKT * 4);
    int*   bbase     = (int*)carve((NBKT + 1) * 4);
    int*   csr       = (int*)carve((size_t)NE * 4);
    unsigned short* Wt1 = (unsigned short*)carve(128 * 256 * 2);
    unsigned short* Wt2 = (unsigned short*)carve(128 * 256 * 2);
    unsigned short* Wt3 = (unsigned short*)carve(128 * 256 * 2);
    unsigned short* xb    = (unsigned short*)carve((size_t)NN * DIM * 2);
    unsigned short* h1b   = (unsigned short*)carve((size_t)NN * DIM * 2);
    unsigned short* h2b   = xb;          // x dead after layer-2 own-feat reads
    int*   binned    = (int*)h1b;        // binned (6.4 MB) dead before k_gl<0> #1

    k_prep<<<NBLK + CASTB + CWB, 256, 0, stream>>>(x, xb, dst, hist,
                                                   W1l, W1r, W2l, W2r, W3l, W3r,
                                                   Wt1, Wt2, Wt3);
    k_scanrow<<<NBKT, 512, 0, stream>>>(hist, row_total);
    k_bin2<<<NBLK, 256, 0, stream>>>(src, dst, hist, row_total, bbase, binned);
    k_build<<<NBKT, 256, 0, stream>>>(binned, bbase, csr, meta, tickets);

    // layer 1: h1 = relu(Wl*mean(xb) + Wr*xb + b)
    k_gl<0><<<FGB, 1024, 0, stream>>>(xb, meta, csr, Wt1, b1, (void*)h1b, tickets);
    // layer 2: h2 = relu(Wl*mean(h1) + Wr*h1 + b)   (h2b aliases xb)
    k_gl<0><<<FGB, 1024, 0, stream>>>(h1b, meta, csr, Wt2, b2, (void*)h2b, tickets + FGB);
    // layer 3: dx_dt = Wl*mean(h2) + Wr*h2 + b      (fp32 out)
    k_gl<1><<<FGB, 1024, 0, stream>>>(h2b, meta, csr, Wt3, b3, d_out, tickets + 2 * FGB);
}

// Round 12
// 417.858 us; speedup vs baseline: 1.2775x; 1.2359x over previous
//
#include <hip/hip_runtime.h>

#define NN   100000
#define NE   1600000
#define DIM  128
#define NBKT 391                  // ceil(NN/256) buckets of 256 nodes
#define EPB  4096                 // edges per binning block (R10-proven: -27us)
#define NBLK 391                  // ceil(NE/EPB)
#define NTILES (NN / 16)          // 6250 node-tiles of 16 rows
#define CASTB 12500               // cast_x blocks (NN*DIM/4/256)
#define CWB   384                 // castw blocks (3*128*256/256)

// Ledger: dense gather (1 node/wave, 4 slots x 16 chunks, 2 chains) = 58us
// structural ceiling (~7TB/s L2 random-line service; R0 chains / R2 nt /
// R3-R6 sliced all bracket it).  Fusion arc falsified: R9 static fused = 96us
// (barrier-coupled block), R11 ticket fused = 121us (global atomic on chain
// head) -- independent 256-thread gather waves are strictly better.  R12 =
// R8 split pipeline (445.5us banked) + EPB 4096 prep parallelism (R10: -27us).

typedef short          s16x8 __attribute__((ext_vector_type(8)));
typedef unsigned short u16x8 __attribute__((ext_vector_type(8)));
typedef float          f32x4 __attribute__((ext_vector_type(4)));

__device__ __forceinline__ unsigned short f2b(float f) {
    unsigned u = __float_as_uint(f);
    unsigned r = ((u >> 16) & 1u) + 0x7FFFu;   // RNE
    return (unsigned short)((u + r) >> 16);
}
__device__ __forceinline__ float b2f(unsigned short h) {
    return __uint_as_float(((unsigned)h) << 16);
}

// ---- fused prep: [0,NBLK) hist | [NBLK,NBLK+CASTB) cast_x | rest castw ----
__global__ void k_prep(const float* __restrict__ x, unsigned short* __restrict__ xb,
                       const int* __restrict__ dst, int* __restrict__ hist,
                       const float* __restrict__ W1l, const float* __restrict__ W1r,
                       const float* __restrict__ W2l, const float* __restrict__ W2r,
                       const float* __restrict__ W3l, const float* __restrict__ W3r,
                       unsigned short* __restrict__ Wt1, unsigned short* __restrict__ Wt2,
                       unsigned short* __restrict__ Wt3) {
    __shared__ int lh[NBKT];
    int t = threadIdx.x, b = blockIdx.x;
    if (b < NBLK) {
        // bucket histogram -> hist[k*NBLK + b] (bucket-major)
        for (int j = t; j < NBKT; j += 256) lh[j] = 0;
        __syncthreads();
        int base = b * EPB;
        int end = base + EPB; if (end > NE) end = NE;
        for (int i = base + t; i < end; i += 256) atomicAdd(&lh[dst[i] >> 8], 1);
        __syncthreads();
        for (int j = t; j < NBKT; j += 256) hist[j * NBLK + b] = lh[j];
    } else if (b < NBLK + CASTB) {
        // fp32 -> bf16 feature cast, dense layout (fully sequential both sides)
        int i = (b - NBLK) * 256 + t;
        float4 v = ((const float4*)x)[i];
        ushort4 o;
        o.x = f2b(v.x); o.y = f2b(v.y); o.z = f2b(v.z); o.w = f2b(v.w);
        ((ushort4*)xb)[i] = o;
    } else {
        // weight cast: Wt[n][k] = bf16( k<128 ? Wl[k][n] : Wr[k-128][n] )
        int i = (b - NBLK - CASTB) * 256 + t;   // 3 * 128 * 256
        int L = i >> 15;
        int rem = i & 32767;
        int n = rem >> 8;
        int k = rem & 255;
        const float* Wl = (L == 0) ? W1l : (L == 1) ? W2l : W3l;
        const float* Wr = (L == 0) ? W1r : (L == 1) ? W2r : W3r;
        unsigned short* Wt = (L == 0) ? Wt1 : (L == 1) ? Wt2 : Wt3;
        float v = (k < 128) ? Wl[k * 128 + n] : Wr[(k - 128) * 128 + n];
        Wt[n * 256 + k] = f2b(v);
    }
}

// ---- phase 2a: per-bucket row scan (exclusive over the 391 block counts) ----
__global__ void k_scanrow(int* __restrict__ hist, int* __restrict__ row_total) {
    __shared__ int sh[512];
    int k = blockIdx.x, t = threadIdx.x;
    int v = (t < NBLK) ? hist[k * NBLK + t] : 0;
    sh[t] = v;
    __syncthreads();
    for (int off = 1; off < 512; off <<= 1) {
        int a = (t >= off) ? sh[t - off] : 0;
        __syncthreads();
        sh[t] += a;
        __syncthreads();
    }
    if (t < NBLK) hist[k * NBLK + t] = sh[t] - v;   // exclusive within row
    if (t == 511) row_total[k] = sh[511];
}

// ---- phase 3: bin edges; bucket-base scan folded in (pair-blocked LDS scan)
// Each block recomputes the 391-total exclusive scan (~1us, concurrent);
// block 0 persists bbase for k_build.  word = (src<<8)|(dst&255).
__global__ void k_bin2(const int* __restrict__ src, const int* __restrict__ dst,
                       const int* __restrict__ hist, const int* __restrict__ row_total,
                       int* __restrict__ bbase, int* __restrict__ binned) {
    __shared__ int s_base[NBKT];
    __shared__ int s_cnt[NBKT];
    __shared__ int ps[256];
    int t = threadIdx.x, b = blockIdx.x;
    // pair-blocked exclusive scan of row_total[0..NBKT)
    int a0 = (2 * t     < NBKT) ? row_total[2 * t]     : 0;
    int a1 = (2 * t + 1 < NBKT) ? row_total[2 * t + 1] : 0;
    ps[t] = a0 + a1;
    __syncthreads();
    for (int off = 1; off < 256; off <<= 1) {
        int v = (t >= off) ? ps[t - off] : 0;
        __syncthreads();
        ps[t] += v;
        __syncthreads();
    }
    int pe = ps[t] - (a0 + a1);            // exclusive pair-prefix
    if (2 * t     < NBKT) s_base[2 * t]     = pe;
    if (2 * t + 1 < NBKT) s_base[2 * t + 1] = pe + a0;
    __syncthreads();
    if (b == 0) {                          // persist for k_build
        for (int j = t; j < NBKT; j += 256) bbase[j] = s_base[j];
        if (t == 0) bbase[NBKT] = NE;
    }
    for (int j = t; j < NBKT; j += 256) {
        s_base[j] += hist[j * NBLK + b];
        s_cnt[j] = 0;
    }
    __syncthreads();
    int base = b * EPB;
    int end = base + EPB; if (end > NE) end = NE;
    for (int i = base + t; i < end; i += 256) {
        int d = dst[i];
        int k = d >> 8;
        int w = (src[i] << 8) | (d & 255);
        int lpos = atomicAdd(&s_cnt[k], 1);
        binned[s_base[k] + lpos] = w;
    }
}

// ---- per-bucket CSR build: LDS degree hist + scan + staged coalesced write.
// Gather metadata packed per node: meta = {row_start, deg, deg_inv_bits, 0}.
__global__ void k_build(const int* __restrict__ binned,
                        const int* __restrict__ bucket_base,
                        int* __restrict__ csr, int4* __restrict__ meta) {
    __shared__ int s_deg[256], s_scan[256], s_cur[256];
    __shared__ int stage[8192];
    int b = blockIdx.x, t = threadIdx.x;
    int base = bucket_base[b], end = bucket_base[b + 1];
    int cnt = end - base;
    s_deg[t] = 0;
    __syncthreads();
    for (int i = t; i < cnt; i += 256)
        atomicAdd(&s_deg[binned[base + i] & 255], 1);
    __syncthreads();
    s_scan[t] = s_deg[t];
    __syncthreads();
    for (int off = 1; off < 256; off <<= 1) {
        int a = (t >= off) ? s_scan[t - off] : 0;
        __syncthreads();
        s_scan[t] += a;
        __syncthreads();
    }
    int excl = s_scan[t] - s_deg[t];
    s_cur[t] = excl;
    int node = b * 256 + t;
    if (node < NN) {
        int d = s_deg[t];
        float di = (d > 0) ? 1.0f / (float)d : 0.0f;
        int4 M; M.x = base + excl; M.y = d; M.z = __float_as_int(di); M.w = 0;
        meta[node] = M;
    }
    __syncthreads();
    for (int i = t; i < cnt; i += 256) {
        int w = binned[base + i];           // L2-hot second read
        int pos = atomicAdd(&s_cur[w & 255], 1);
        int s = w >> 8;
        if (pos < 8192) stage[pos] = s;
        else            csr[base + pos] = s;   // overflow fallback (not expected)
    }
    __syncthreads();
    int m = cnt < 8192 ? cnt : 8192;
    for (int i = t; i < m; i += 256) csr[base + i] = stage[i];
}

// ---- mean aggregation: one wave per node; 4 neighbor slots x 16 col-chunks ----
// 2 independent load+accumulate chains per lane (R5-proven: more chains regress
// — random-access request path saturates ~7 TB/s; extra VGPRs cost occupancy).
// int4 meta: single 16B load replaces 3 scalar loads at the chain head.
__global__ void k_gather(const unsigned short* __restrict__ feat,
                         const int4* __restrict__ meta,
                         const int* __restrict__ csr,
                         unsigned short* __restrict__ mean) {
    int lane = threadIdx.x & 63;
    int wv   = threadIdx.x >> 6;
    int n    = blockIdx.x * 4 + wv;        // NN % 4 == 0, grid exact
    int q = lane >> 4, c = lane & 15;      // q: neighbor slot, c: 16B column chunk
    int4 M = meta[n];
    int base = M.x;
    int d    = M.y;
    float s  = __int_as_float(M.z);
    float acc0[8], acc1[8];
#pragma unroll
    for (int t = 0; t < 8; t++) { acc0[t] = 0.0f; acc1[t] = 0.0f; }
    const u16x8* fp = (const u16x8*)feat;
    int j = q;
    for (; j + 4 < d; j += 8) {
        int s0 = csr[base + j];
        int s1 = csr[base + j + 4];
        u16x8 v0 = fp[s0 * 16 + c];
        u16x8 v1 = fp[s1 * 16 + c];
#pragma unroll
        for (int t = 0; t < 8; t++) { acc0[t] += b2f(v0[t]); acc1[t] += b2f(v1[t]); }
    }
    if (j < d) {
        int s0 = csr[base + j];
        u16x8 v0 = fp[s0 * 16 + c];
#pragma unroll
        for (int t = 0; t < 8; t++) acc0[t] += b2f(v0[t]);
    }
#pragma unroll
    for (int t = 0; t < 8; t++) acc0[t] += acc1[t];
#pragma unroll
    for (int t = 0; t < 8; t++) {
        acc0[t] += __shfl_xor(acc0[t], 16, 64);
        acc0[t] += __shfl_xor(acc0[t], 32, 64);
    }
    if (q == 0) {
        u16x8 o;
#pragma unroll
        for (int t = 0; t < 8; t++) o[t] = f2b(acc0[t] * s);
        ((u16x8*)mean)[n * 16 + c] = o;
    }
}

// ---- fused linear v3: LDS weights as MFMA *A*-operand; D[outdim][node] ----
// acc = mfma(W_frag, X_frag): col(lane&15)=node, row(quad*4+r)=outdim ->
// each lane holds 4 consecutive outdims for one node -> packed 8B/16B stores.
// MODE 0: relu, bf16 output; MODE 1: no act, fp32 output
template <int MODE>
__global__ void __launch_bounds__(512)
k_lin(const unsigned short* __restrict__ meanb,
      const unsigned short* __restrict__ hb,
      const unsigned short* __restrict__ Wt,
      const float* __restrict__ bias, void* __restrict__ out) {
    __shared__ s16x8 sW[4096];             // 64 KB
    int t = threadIdx.x;
    const s16x8* wp = (const s16x8*)Wt;
    // stage in fragment order: chunk ci -> frag (ci>>6), lane (ci&63)
    // A-frag for tile (mt,kt): m = mt*16 + (lane&15), k-chunk = kt*4 + (lane>>4)
#pragma unroll
    for (int it = 0; it < 8; it++) {
        int ci = it * 512 + t;
        int frag = ci >> 6, ln = ci & 63;
        int mt = frag >> 3, kt = frag & 7;
        int m = mt * 16 + (ln & 15);
        int kc = kt * 4 + (ln >> 4);
        sW[ci] = wp[m * 32 + kc];
    }
    __syncthreads();

    int lane = t & 63;
    int wv   = t >> 6;
    int tile = blockIdx.x * 8 + wv;        // node tile (16 nodes)
    if (tile >= NTILES) return;
    int n0 = tile * 16;
    int q = lane >> 4, c = lane & 15;
    const s16x8* mp = (const s16x8*)meanb;
    const s16x8* hp = (const s16x8*)hb;
    int row = n0 + c;                      // B: n(node) = lane&15, k-chunk = quad*8
    s16x8 B[8];
#pragma unroll
    for (int kt = 0; kt < 4; kt++) B[kt] = mp[row * 16 + kt * 4 + q];
#pragma unroll
    for (int kt = 0; kt < 4; kt++) B[4 + kt] = hp[row * 16 + kt * 4 + q];
    const f32x4* bp = (const f32x4*)bias;
#pragma unroll
    for (int mt = 0; mt < 8; mt++) {
        f32x4 acc = {0.f, 0.f, 0.f, 0.f};
#pragma unroll
        for (int kt = 0; kt < 8; kt++)
            acc = __builtin_amdgcn_mfma_f32_16x16x32_bf16(sW[(mt * 8 + kt) * 64 + lane],
                                                          B[kt], acc, 0, 0, 0);
        f32x4 bv = bp[mt * 4 + q];         // outdims mt*16+q*4 .. +3
        int node = n0 + c;
        if (MODE == 0) {
            ushort4 o;
            float v0 = acc[0] + bv[0]; if (v0 < 0.f) v0 = 0.f;
            float v1 = acc[1] + bv[1]; if (v1 < 0.f) v1 = 0.f;
            float v2 = acc[2] + bv[2]; if (v2 < 0.f) v2 = 0.f;
            float v3 = acc[3] + bv[3]; if (v3 < 0.f) v3 = 0.f;
            o.x = f2b(v0); o.y = f2b(v1); o.z = f2b(v2); o.w = f2b(v3);
            ((ushort4*)out)[node * 32 + mt * 4 + q] = o;
        } else {
            f32x4 v;
#pragma unroll
            for (int r = 0; r < 4; r++) v[r] = acc[r] + bv[r];
            ((f32x4*)out)[node * 32 + mt * 4 + q] = v;
        }
    }
}

extern "C" void kernel_launch(void* const* d_in, const int* in_sizes, int n_in,
                              void* d_out, int out_size, void* d_ws, size_t ws_size,
                              hipStream_t stream) {
    const float* x   = (const float*)d_in[1];
    const int*   ei  = (const int*)d_in[2];
    const int*   src = ei;
    const int*   dst = ei + NE;
    const float* W1l = (const float*)d_in[3];
    const float* W1r = (const float*)d_in[4];
    const float* b1  = (const float*)d_in[5];
    const float* W2l = (const float*)d_in[6];
    const float* W2r = (const float*)d_in[7];
    const float* b2  = (const float*)d_in[8];
    const float* W3l = (const float*)d_in[9];
    const float* W3r = (const float*)d_in[10];
    const float* b3  = (const float*)d_in[11];

    // workspace carve (all 256B aligned)
    char* w = (char*)d_ws;
    auto carve = [&](size_t bytes) {
        void* p = (void*)w;
        w += (bytes + 255) & ~(size_t)255;
        return p;
    };
    int4*  meta      = (int4*)carve((size_t)NN * 16);
    int*   hist      = (int*)carve((size_t)NBKT * NBLK * 4);
    int*   row_total = (int*)carve(NBKT * 4);
    int*   bbase     = (int*)carve((NBKT + 1) * 4);
    int*   csr       = (int*)carve((size_t)NE * 4);
    unsigned short* Wt1 = (unsigned short*)carve(128 * 256 * 2);
    unsigned short* Wt2 = (unsigned short*)carve(128 * 256 * 2);
    unsigned short* Wt3 = (unsigned short*)carve(128 * 256 * 2);
    unsigned short* xb    = (unsigned short*)carve((size_t)NN * DIM * 2);
    unsigned short* meanb = (unsigned short*)carve((size_t)NN * DIM * 2);
    unsigned short* h1b   = (unsigned short*)carve((size_t)NN * DIM * 2);
    unsigned short* h2b   = xb;          // x dead after layer-2 B-load
    int*   binned    = (int*)meanb;      // binned (6.4 MB) dead before first k_gather

    k_prep<<<NBLK + CASTB + CWB, 256, 0, stream>>>(x, xb, dst, hist,
                                                   W1l, W1r, W2l, W2r, W3l, W3r,
                                                   Wt1, Wt2, Wt3);
    k_scanrow<<<NBKT, 512, 0, stream>>>(hist, row_total);
    k_bin2<<<NBLK, 256, 0, stream>>>(src, dst, hist, row_total, bbase, binned);
    k_build<<<NBKT, 256, 0, stream>>>(binned, bbase, csr, meta);

    const int GB = NN / 4;                  // gather blocks (4 waves = 4 nodes each)
    const int LB = (NTILES + 7) / 8;        // k_lin blocks (8 waves = 8 tiles each)

    // layer 1: mean over xb -> h1 = relu(lin)
    k_gather<<<GB, 256, 0, stream>>>(xb, meta, csr, meanb);
    k_lin<0><<<LB, 512, 0, stream>>>(meanb, xb, Wt1, b1, (void*)h1b);
    // layer 2: mean over h1 -> h2 = relu(lin)
    k_gather<<<GB, 256, 0, stream>>>(h1b, meta, csr, meanb);
    k_lin<0><<<LB, 512, 0, stream>>>(meanb, h1b, Wt2, b2, (void*)h2b);
    // layer 3: mean over h2 -> dx_dt (fp32, no activation)
    k_gather<<<GB, 256, 0, stream>>>(h2b, meta, csr, meanb);
    k_lin<1><<<LB, 512, 0, stream>>>(meanb, h2b, Wt3, b3, d_out);
}